// Round 8
// baseline (523.287 us; speedup 1.0000x reference)
//
#include <hip/hip_runtime.h>
#include <stdint.h>

#define DIM 1024
#define NH 16
#define DH 64
#define BATCH 4
#define SEQ 2048
#define MROWS (BATCH*SEQ)  // 8192

typedef _Float16 half8 __attribute__((ext_vector_type(8)));
typedef __fp16 fp16x2 __attribute__((ext_vector_type(2)));
typedef float f32x4 __attribute__((ext_vector_type(4)));
typedef float f32x16 __attribute__((ext_vector_type(16)));

__device__ __forceinline__ unsigned short f2h(float f) {
    union { _Float16 h; unsigned short u; } c; c.h = (_Float16)f; return c.u;
}
__device__ __forceinline__ unsigned int pk2u(float a, float b) {
    union { fp16x2 h; unsigned int u; } c;
    c.h = __builtin_amdgcn_cvt_pkrtz(a, b);
    return c.u;
}
// raw v_exp_f32 (1 inst; exp2f without -ffast-math goes through ocml libm)
__device__ __forceinline__ float fexp2(float x) {
    return __builtin_amdgcn_exp2f(x);
}
// async 16B/lane global->LDS (lds dest = wave-uniform base + lane*16)
__device__ __forceinline__ void gl_lds16(const unsigned short* g, unsigned short* l) {
    __builtin_amdgcn_global_load_lds(
        (__attribute__((address_space(1))) void*)(void*)g,
        (__attribute__((address_space(3))) void*)(void*)l,
        16, 0, 0);
}
__device__ __forceinline__ half8 u4h8(unsigned a, unsigned b, unsigned c, unsigned d) {
    union { unsigned u[4]; half8 h; } x;
    x.u[0] = a; x.u[1] = b; x.u[2] = c; x.u[3] = d;
    return x.h;
}

// ---------------- cast / prep kernels ----------------

__global__ void cast_x_kernel(const float* __restrict__ x,
                              unsigned short* __restrict__ xh, int n4) {
    int i = blockIdx.x * blockDim.x + threadIdx.x;
    if (i >= n4) return;
    float4 v = reinterpret_cast<const float4*>(x)[i];
    uint2 o;
    o.x = pk2u(v.x, v.y);
    o.y = pk2u(v.z, v.w);
    reinterpret_cast<uint2*>(xh)[i] = o;
}

// W[mat][h][d][e] (fp32) -> wt[mat][h][e][d] (f16), LDS-tiled transpose
__global__ __launch_bounds__(256) void prep_wqkv_kernel(
    const float* __restrict__ Wq, const float* __restrict__ Wk,
    const float* __restrict__ Wv, unsigned short* __restrict__ wt)
{
    __shared__ unsigned short tile[64][65];
    const int d0 = blockIdx.x * 64;
    const int h = blockIdx.y;
    const int mat = blockIdx.z;
    const float* W = (mat == 0) ? Wq : ((mat == 1) ? Wk : Wv);
    const int c = threadIdx.x & 63;
    const int rr = threadIdx.x >> 6;
#pragma unroll
    for (int p = 0; p < 16; p++) {
        int dl = p * 4 + rr;
        tile[dl][c] = f2h(W[((size_t)h * 1024 + d0 + dl) * 64 + c]);
    }
    __syncthreads();
#pragma unroll
    for (int p = 0; p < 16; p++) {
        int el = p * 4 + rr;
        wt[(((size_t)(mat * NH + h) * 64) + el) * DIM + d0 + c] = tile[c][el];
    }
}

// Wo[d][o] -> wot[o][d] (f16), LDS-tiled transpose
__global__ __launch_bounds__(256) void prep_wo_kernel(
    const float* __restrict__ Wo, unsigned short* __restrict__ wot)
{
    __shared__ unsigned short tile[64][65];
    const int d0 = blockIdx.x * 64;
    const int o0 = blockIdx.y * 64;
    const int c = threadIdx.x & 63;
    const int rr = threadIdx.x >> 6;
#pragma unroll
    for (int p = 0; p < 16; p++) {
        int dl = p * 4 + rr;
        tile[dl][c] = f2h(Wo[(size_t)(d0 + dl) * DIM + o0 + c]);
    }
    __syncthreads();
#pragma unroll
    for (int p = 0; p < 16; p++) {
        int ol = p * 4 + rr;
        wot[(size_t)(o0 + ol) * DIM + d0 + c] = tile[c][ol];
    }
}

// Vb [b][h][s][dh] -> Vt [b][h][dh][s], LDS-tiled transpose
__global__ __launch_bounds__(256) void transpose_v_kernel(
    const unsigned short* __restrict__ Vb, unsigned short* __restrict__ Vt)
{
    __shared__ unsigned short tile[64][65];
    const int s0 = blockIdx.x * 64;
    const size_t bh = (size_t)blockIdx.z * NH + blockIdx.y;
    const int c = threadIdx.x & 63;
    const int rr = threadIdx.x >> 6;
    const unsigned short* src = Vb + bh * SEQ * DH;
    unsigned short* dst = Vt + bh * DH * SEQ;
#pragma unroll
    for (int p = 0; p < 16; p++) {
        int sl = p * 4 + rr;
        tile[sl][c] = src[(size_t)(s0 + sl) * DH + c];
    }
    __syncthreads();
#pragma unroll
    for (int p = 0; p < 16; p++) {
        int dr = p * 4 + rr;
        dst[(size_t)dr * SEQ + s0 + c] = tile[c][dr];
    }
}

// ---------------- QKV projection GEMM (staged, 128x128, BK=32) ----
__global__ __launch_bounds__(256) void qkv_gemm_kernel(
    const unsigned short* __restrict__ xh,   // [8192][1024] f16
    const unsigned short* __restrict__ wt,   // [3][16][64][1024] f16
    const float* __restrict__ bq, const float* __restrict__ bk,
    const float* __restrict__ bv,
    unsigned short* __restrict__ Qb,         // [B][H][S][DH] (scaled)
    unsigned short* __restrict__ Kb,         // [B][H][S][DH]
    unsigned short* __restrict__ Vb)         // [B][H][S][DH]
{
    const int rowblk = blockIdx.x;
    const int hpair = blockIdx.y;
    const int mat = blockIdx.z;
    const int wave = threadIdx.x >> 6;
    const int lane = threadIdx.x & 63;
    const int quad = lane >> 4;
    const int lr = lane & 15;
    const int mhalf = wave & 1;
    const int nhalf = wave >> 1;

    __shared__ __align__(16) unsigned short Ab[2][128 * 32];
    __shared__ __align__(16) unsigned short Bt[2][128 * 32];

    const unsigned short* Asrc = xh + (size_t)rowblk * 128 * DIM;
    const unsigned short* Bsrc = wt + (size_t)(mat * NH + hpair * 2) * DH * DIM;

    const int srow = lane >> 2;    // 0..15 row within 16-row group
    const int scs = lane & 3;      // chunk slot 0..3 (8 f16 each)

    f32x4 acc[4][4];
#pragma unroll
    for (int mt = 0; mt < 4; mt++)
#pragma unroll
        for (int nt = 0; nt < 4; nt++) acc[mt][nt] = (f32x4){0.f, 0.f, 0.f, 0.f};

    auto stage = [&](int k0, int sel) {
#pragma unroll
        for (int jj = 0; jj < 2; jj++) {
            const int j = wave * 2 + jj;            // 0..7 (16 rows each)
            const int r = j * 16 + srow;            // 0..127
            const int cg = scs ^ ((r >> 1) & 3);    // swizzled source chunk
            gl_lds16(Asrc + (size_t)r * DIM + k0 + cg * 8, &Ab[sel][j * 512]);
            gl_lds16(Bsrc + (size_t)r * DIM + k0 + cg * 8, &Bt[sel][j * 512]);
        }
    };

    stage(0, 0);
    __syncthreads();

    for (int i = 0; i < DIM / 32; i++) {
        const int sel = i & 1;
        if (i + 1 < DIM / 32) stage((i + 1) * 32, sel ^ 1);

        half8 af[4], bf[4];
#pragma unroll
        for (int mt = 0; mt < 4; mt++) {
            const int row = mhalf * 64 + mt * 16 + lr;
            const int slot = quad ^ ((row >> 1) & 3);
            af[mt] = *reinterpret_cast<const half8*>(&Ab[sel][row * 32 + slot * 8]);
        }
#pragma unroll
        for (int nt = 0; nt < 4; nt++) {
            const int row = nhalf * 64 + nt * 16 + lr;
            const int slot = quad ^ ((row >> 1) & 3);
            bf[nt] = *reinterpret_cast<const half8*>(&Bt[sel][row * 32 + slot * 8]);
        }
#pragma unroll
        for (int mt = 0; mt < 4; mt++)
#pragma unroll
            for (int nt = 0; nt < 4; nt++)
                acc[mt][nt] = __builtin_amdgcn_mfma_f32_16x16x32_f16(
                    af[mt], bf[nt], acc[mt][nt], 0, 0, 0);
        __syncthreads();
    }

    const float* bias = (mat == 0) ? bq : ((mat == 1) ? bk : bv);
    const float scale = (mat == 0) ? 0.1803368801111601f : 1.0f;  // 0.125*log2(e)
    unsigned short* outp = (mat == 0) ? Qb : ((mat == 1) ? Kb : Vb);
    const int rowBase = rowblk * 128 + mhalf * 64;
    const int bb = rowBase / SEQ;
    const int sBase = rowBase % SEQ;

#pragma unroll
    for (int mt = 0; mt < 4; mt++) {
        const int s0 = sBase + mt * 16 + quad * 4;
#pragma unroll
        for (int nt = 0; nt < 4; nt++) {
            const int e = nhalf * 64 + nt * 16 + lr;   // 0..127 in head pair
            const int head = hpair * 2 + (e >> 6);
            const int n = e & 63;
            const float bvl = bias[head * DH + n];
            const size_t base = (size_t)(bb * NH + head) * SEQ * DH;
#pragma unroll
            for (int r = 0; r < 4; r++) {
                outp[base + (size_t)(s0 + r) * DH + n] = f2h((acc[mt][nt][r] + bvl) * scale);
            }
        }
    }
}

// ---------------- flash attention (32x32 MFMA, shfl P-exchange) --------------
// grid (64 hb, 8 qblocks of 256 rows), block 256 = 4 waves, 64 q/wave.
// blockid = qblk*64 + hb -> XCD = hb%8: all q-blocks of one (b,h) share an XCD
// (K/V L2-resident). K/V staged to LDS dbuf via global_load_lds. S^T = K.Q^T
// with 32x32x16 MFMA (C: col=lane&31=q, row=key=(reg&3)+8*(reg>>2)+4*(lane>>5)).
// P converts from C-layout to PV B-layout with a single lane^32 exchange:
// B-chunk c pair u <- P2[4c+2h+(u&1)] from half u>>1 (h = target lane>>5).
// No P LDS buffer at all; l accumulated per-lane, one shfl at the end.
__global__ __launch_bounds__(256, 2) void attn_kernel(
    const unsigned short* __restrict__ Qb,   // [B][H][S][DH] scaled by 0.125*log2e
    const unsigned short* __restrict__ Kb,   // [B][H][S][DH]
    const unsigned short* __restrict__ Vt,   // [B][H][DH][S]
    unsigned short* __restrict__ Ob)         // [B*S][DIM] f16
{
    const int hb = blockIdx.x;               // h + 16*b
    const int h = hb & 15;
    const int bb = hb >> 4;
    const int wave = threadIdx.x >> 6;
    const int lane = threadIdx.x & 63;
    const int l31 = lane & 31;
    const int hh = lane >> 5;                // half: 0 or 1
    const int qBase = blockIdx.y * 256 + wave * 64;

    const size_t bh = (size_t)(bb * NH + h);
    const unsigned short* Qh = Qb + bh * SEQ * DH;
    const unsigned short* Kh = Kb + bh * SEQ * DH;
    const unsigned short* Vh = Vt + bh * DH * SEQ;

    __shared__ __align__(16) unsigned short Kbuf[2][64 * 64];  // [key][dh] swizzled
    __shared__ __align__(16) unsigned short Vbuf[2][64 * 64];  // [dh][s]  swizzled

    // staging offsets (loop-invariant): wave stages 16 rows of K and of V
    const int srow = lane >> 3;   // 0..7
    const int scs = lane & 7;     // dest slot 0..7 (granules of 8 f16)
    const int cg = scs ^ srow;    // source granule (slot stores g = slot^(row&7))
    int koff[2], voff[2];
#pragma unroll
    for (int jj = 0; jj < 2; jj++) {
        const int r = wave * 16 + jj * 8 + srow;   // 0..63
        koff[jj] = r * DH + cg * 8;
        voff[jj] = r * SEQ + cg * 8;
    }
    auto stage = [&](int kt, int sel) {
        gl_lds16(Kh + (size_t)kt * DH + koff[0], &Kbuf[sel][wave * 1024]);
        gl_lds16(Kh + (size_t)kt * DH + koff[1], &Kbuf[sel][wave * 1024 + 512]);
        gl_lds16(Vh + kt + voff[0], &Vbuf[sel][wave * 1024]);
        gl_lds16(Vh + kt + voff[1], &Vbuf[sel][wave * 1024 + 512]);
    };

    // Q B-frags (loop-invariant): B[k=dh][n=q]: lane n=l31, k = kc*16+8*hh+j
    half8 qf[2][4];
#pragma unroll
    for (int qt = 0; qt < 2; qt++)
#pragma unroll
        for (int kc = 0; kc < 4; kc++)
            qf[qt][kc] = *reinterpret_cast<const half8*>(
                Qh + (size_t)(qBase + qt * 32 + l31) * DH + kc * 16 + hh * 8);

    f32x16 o[2][2];   // O^T tiles [dh-sub][q-tile]
#pragma unroll
    for (int ds = 0; ds < 2; ds++)
#pragma unroll
        for (int qt = 0; qt < 2; qt++)
#pragma unroll
            for (int r = 0; r < 16; r++) o[ds][qt][r] = 0.f;
    float lsum[2] = {0.f, 0.f};

    const f32x16 zf16 = {0.f};

    auto compute = [&](int sel) {
        // K A-frags: lane m=key=ks*32+l31, k-chunk granule kc*2+hh, swizzled
        half8 kf[2][4];
#pragma unroll
        for (int ks = 0; ks < 2; ks++)
#pragma unroll
            for (int kc = 0; kc < 4; kc++) {
                const int row = ks * 32 + l31;
                const int slot = (kc * 2 + hh) ^ (row & 7);
                kf[ks][kc] = *reinterpret_cast<const half8*>(&Kbuf[sel][row * 64 + slot * 8]);
            }
        // V A-frags issued early (latency hides under QK/softmax)
        half8 vf[2][4];
#pragma unroll
        for (int ds = 0; ds < 2; ds++)
#pragma unroll
            for (int c = 0; c < 4; c++) {
                const int row = ds * 32 + l31;
                const int slot = (c * 2 + hh) ^ (row & 7);
                vf[ds][c] = *reinterpret_cast<const half8*>(&Vbuf[sel][row * 64 + slot * 8]);
            }

        unsigned BB[2][4][4];   // PV B-frags [qt][chunk][pair]
#pragma unroll
        for (int qt = 0; qt < 2; qt++) {
            f32x16 sacc[2];
#pragma unroll
            for (int kc = 0; kc < 4; kc++)
#pragma unroll
                for (int ks = 0; ks < 2; ks++)
                    sacc[ks] = __builtin_amdgcn_mfma_f32_32x32x16_f16(
                        kf[ks][kc], qf[qt][kc], kc ? sacc[ks] : zf16, 0, 0, 0);

            // exp2 + pack to P2 (key pairs) + l partials
            unsigned P2[2][8];
#pragma unroll
            for (int ks = 0; ks < 2; ks++)
#pragma unroll
                for (int j = 0; j < 8; j++) {
                    float p0 = fexp2(sacc[ks][2 * j]);
                    float p1 = fexp2(sacc[ks][2 * j + 1]);
                    lsum[qt] += p0 + p1;
                    P2[ks][j] = pk2u(p0, p1);
                }

            // C-layout -> B-layout via lane^32 exchange.
            // chunk c (16 keys): ks = c>>1, cl = c&1:
            //   own0 = P2[4cl+2h], own1 = P2[4cl+2h+1] (h = own half)
            //   xa = shfl_xor(oth0,32), xb = shfl_xor(oth1,32) where othX uses 2*(1-h)
            //   BB[0] = h?xa:own0; BB[1] = h?xb:own1; BB[2] = h?own0:xa; BB[3] = h?own1:xb
#pragma unroll
            for (int c = 0; c < 4; c++) {
                const int ks = c >> 1, cl = c & 1;
                unsigned own0 = hh ? P2[ks][4 * cl + 2] : P2[ks][4 * cl + 0];
                unsigned own1 = hh ? P2[ks][4 * cl + 3] : P2[ks][4 * cl + 1];
                unsigned oth0 = hh ? P2[ks][4 * cl + 0] : P2[ks][4 * cl + 2];
                unsigned oth1 = hh ? P2[ks][4 * cl + 1] : P2[ks][4 * cl + 3];
                unsigned xa = __shfl_xor((int)oth0, 32);
                unsigned xb = __shfl_xor((int)oth1, 32);
                BB[qt][c][0] = hh ? xa : own0;
                BB[qt][c][1] = hh ? xb : own1;
                BB[qt][c][2] = hh ? own0 : xa;
                BB[qt][c][3] = hh ? own1 : xb;
            }
        }

        // O^T += V.P
#pragma unroll
        for (int c = 0; c < 4; c++)
#pragma unroll
            for (int ds = 0; ds < 2; ds++)
#pragma unroll
                for (int qt = 0; qt < 2; qt++)
                    o[ds][qt] = __builtin_amdgcn_mfma_f32_32x32x16_f16(
                        vf[ds][c],
                        u4h8(BB[qt][c][0], BB[qt][c][1], BB[qt][c][2], BB[qt][c][3]),
                        o[ds][qt], 0, 0, 0);
    };

    stage(0, 0);
    __syncthreads();
    for (int i = 0; i < SEQ / 64; i += 2) {
        stage((i + 1) * 64, 1);
        compute(0);
        __syncthreads();
        if (i + 2 < SEQ / 64) stage((i + 2) * 64, 0);
        compute(1);
        __syncthreads();
    }

    // epilogue: l totals (halves combine), normalize, store O^T
    float inv[2];
#pragma unroll
    for (int qt = 0; qt < 2; qt++) {
        float l = lsum[qt] + __shfl_xor(lsum[qt], 32);
        inv[qt] = 1.f / l;
    }
#pragma unroll
    for (int ds = 0; ds < 2; ds++)
#pragma unroll
        for (int qt = 0; qt < 2; qt++) {
            const int q = qBase + qt * 32 + l31;
            unsigned short* obq = Ob + ((size_t)(bb * SEQ + q)) * DIM + h * DH;
#pragma unroll
            for (int r = 0; r < 4; r++) {
                // regs 4r..4r+3 -> dh = ds*32 + 8r + 4*hh + {0..3}
                uint2 pkd;
                pkd.x = pk2u(o[ds][qt][4 * r] * inv[qt], o[ds][qt][4 * r + 1] * inv[qt]);
                pkd.y = pk2u(o[ds][qt][4 * r + 2] * inv[qt], o[ds][qt][4 * r + 3] * inv[qt]);
                *reinterpret_cast<uint2*>(obq + ds * 32 + 8 * r + 4 * hh) = pkd;
            }
        }
}

// ---------------- output projection (staged, 128x128, BK=32) -------
__global__ __launch_bounds__(256) void out_proj_kernel(
    const unsigned short* __restrict__ Ob,   // [8192][1024] f16
    const unsigned short* __restrict__ wot,  // [1024 out][1024 in] f16
    const float* __restrict__ bo,
    float* __restrict__ out)                 // [8192][1024] fp32
{
    const int rowblk = blockIdx.x;
    const int colblk = blockIdx.y;
    const int wave = threadIdx.x >> 6;
    const int lane = threadIdx.x & 63;
    const int quad = lane >> 4;
    const int lr = lane & 15;
    const int mhalf = wave & 1;
    const int nhalf = wave >> 1;

    __shared__ __align__(16) unsigned short Ab[2][128 * 32];
    __shared__ __align__(16) unsigned short Bt[2][128 * 32];

    const unsigned short* Asrc = Ob + (size_t)rowblk * 128 * DIM;
    const unsigned short* Bsrc = wot + (size_t)colblk * 128 * DIM;

    const int srow = lane >> 2;
    const int scs = lane & 3;

    f32x4 acc[4][4];
#pragma unroll
    for (int mt = 0; mt < 4; mt++)
#pragma unroll
        for (int nt = 0; nt < 4; nt++) acc[mt][nt] = (f32x4){0.f, 0.f, 0.f, 0.f};

    auto stage = [&](int k0, int sel) {
#pragma unroll
        for (int jj = 0; jj < 2; jj++) {
            const int j = wave * 2 + jj;
            const int r = j * 16 + srow;
            const int cg = scs ^ ((r >> 1) & 3);
            gl_lds16(Asrc + (size_t)r * DIM + k0 + cg * 8, &Ab[sel][j * 512]);
            gl_lds16(Bsrc + (size_t)r * DIM + k0 + cg * 8, &Bt[sel][j * 512]);
        }
    };

    stage(0, 0);
    __syncthreads();

    for (int i = 0; i < DIM / 32; i++) {
        const int sel = i & 1;
        if (i + 1 < DIM / 32) stage((i + 1) * 32, sel ^ 1);

        half8 af[4], bf[4];
#pragma unroll
        for (int mt = 0; mt < 4; mt++) {
            const int row = mhalf * 64 + mt * 16 + lr;
            const int slot = quad ^ ((row >> 1) & 3);
            af[mt] = *reinterpret_cast<const half8*>(&Ab[sel][row * 32 + slot * 8]);
        }
#pragma unroll
        for (int nt = 0; nt < 4; nt++) {
            const int row = nhalf * 64 + nt * 16 + lr;
            const int slot = quad ^ ((row >> 1) & 3);
            bf[nt] = *reinterpret_cast<const half8*>(&Bt[sel][row * 32 + slot * 8]);
        }
#pragma unroll
        for (int mt = 0; mt < 4; mt++)
#pragma unroll
            for (int nt = 0; nt < 4; nt++)
                acc[mt][nt] = __builtin_amdgcn_mfma_f32_16x16x32_f16(
                    af[mt], bf[nt], acc[mt][nt], 0, 0, 0);
        __syncthreads();
    }

    const int rowBase = rowblk * 128 + mhalf * 64;
    const int colBase = colblk * 128 + nhalf * 64;
#pragma unroll
    for (int mt = 0; mt < 4; mt++) {
#pragma unroll
        for (int nt = 0; nt < 4; nt++) {
            const int col = colBase + nt * 16 + lr;
            const float bias = bo[col];
#pragma unroll
            for (int r = 0; r < 4; r++) {
                int row = rowBase + mt * 16 + quad * 4 + r;
                out[(size_t)row * DIM + col] = acc[mt][nt][r] + bias;
            }
        }
    }
}

// ---------------- launch ----------------

extern "C" void kernel_launch(void* const* d_in, const int* in_sizes, int n_in,
                              void* d_out, int out_size, void* d_ws, size_t ws_size,
                              hipStream_t stream) {
    const float* x  = (const float*)d_in[0];
    const float* Wq = (const float*)d_in[1];
    const float* Wk = (const float*)d_in[2];
    const float* Wv = (const float*)d_in[3];
    const float* bq = (const float*)d_in[4];
    const float* bk = (const float*)d_in[5];
    const float* bv = (const float*)d_in[6];
    const float* Wo = (const float*)d_in[7];
    const float* bo = (const float*)d_in[8];
    float* out = (float*)d_out;

    unsigned short* xh  = (unsigned short*)d_ws;                 // 8192*1024
    unsigned short* wt  = xh  + (size_t)MROWS * DIM;             // 3*16*64*1024
    unsigned short* wot = wt  + (size_t)3 * NH * DH * DIM;       // 1024*1024
    unsigned short* Qb  = wot + (size_t)DIM * DIM;               // 4*16*2048*64
    unsigned short* Kb  = Qb  + (size_t)BATCH * NH * SEQ * DH;
    unsigned short* Vb  = Kb  + (size_t)BATCH * NH * SEQ * DH;
    unsigned short* Vt  = Vb  + (size_t)BATCH * NH * SEQ * DH;
    unsigned short* Ob  = Vt  + (size_t)BATCH * NH * SEQ * DH;

    {
        int n4 = MROWS * DIM / 4;
        cast_x_kernel<<<(n4 + 255) / 256, 256, 0, stream>>>(x, xh, n4);
    }
    prep_wqkv_kernel<<<dim3(16, NH, 3), 256, 0, stream>>>(Wq, Wk, Wv, wt);
    prep_wo_kernel<<<dim3(16, 16), 256, 0, stream>>>(Wo, wot);
    qkv_gemm_kernel<<<dim3(64, 8, 3), 256, 0, stream>>>(xh, wt, bq, bk, bv, Qb, Kb, Vb);
    transpose_v_kernel<<<dim3(SEQ / 64, NH, BATCH), 256, 0, stream>>>(Vb, Vt);
    attn_kernel<<<dim3(64, SEQ / 256), 256, 0, stream>>>(Qb, Kb, Vt, Ob);
    out_proj_kernel<<<dim3(64, 8), 256, 0, stream>>>(Ob, wot, bo, out);
}